// Round 1
// baseline (716.115 us; speedup 1.0000x reference)
//
#include <hip/hip_runtime.h>

// LIF neuron: v_t = ALPHA*v_{t-1} + (x_t . w) - V_TH*z_{t-1}; z_t = 1[v_t > V_TH]
// x: [B=128, T=1000, N=1024] fp32, w: [N] fp32.
// Out: v_seq [B,T] then z_seq [B,T], flat fp32 (256000 elements).

#define ALPHA 0.995f
#define V_TH 2.0f

constexpr int B = 128;
constexpr int T = 1000;
constexpr int N = 1024;

// Kernel 1: drive_t[t*B + b] = dot(x[b,t,:], w)  -- one wave per (b,t) row.
// 524 MB of x read once, fully coalesced float4 loads (16 B/lane).
// Double accumulation: keeps drive within ~1e-7 of exact so we minimize
// spike-flip divergence vs the np reference (a flip costs absmax >= 1.0).
__global__ __launch_bounds__(256) void lif_dot_kernel(
    const float* __restrict__ x, const float* __restrict__ w,
    float* __restrict__ drive_t) {
    const int wave = threadIdx.x >> 6;     // 4 waves/block, 1 row each
    const int lane = threadIdx.x & 63;
    const long long row = (long long)blockIdx.x * 4 + wave;  // b*T + t
    const float* xr = x + row * N;

    double acc = 0.0;
#pragma unroll
    for (int it = 0; it < 4; ++it) {
        const int idx = it * 256 + lane * 4;           // 64 lanes * 4 floats
        const float4 xv = *(const float4*)(xr + idx);  // coalesced 16B/lane
        const float4 wv = *(const float4*)(w + idx);   // L1-resident (4 KB)
        acc += (double)xv.x * (double)wv.x;
        acc += (double)xv.y * (double)wv.y;
        acc += (double)xv.z * (double)wv.z;
        acc += (double)xv.w * (double)wv.w;
    }
    // wave64 butterfly reduction
#pragma unroll
    for (int off = 32; off >= 1; off >>= 1)
        acc += __shfl_down(acc, off);

    if (lane == 0) {
        const int b = (int)(row / T);
        const int t = (int)(row - (long long)b * T);
        drive_t[t * B + b] = (float)acc;   // [T,B] layout -> coalesced scan reads
    }
}

// Kernel 2: sequential scan over T, one thread per batch element.
// Loads at fixed t are contiguous across the 128 threads; unroll x8 so the
// 8 independent loads pipeline ahead of the dependent 2-op FMA chain.
__global__ __launch_bounds__(128) void lif_scan_kernel(
    const float* __restrict__ drive_t, float* __restrict__ out) {
    const int b = threadIdx.x;             // 0..127
    float* __restrict__ vout = out + (long long)b * T;
    float* __restrict__ zout = out + (long long)B * T + (long long)b * T;

    float v = 0.0f, z = 0.0f;
    for (int t0 = 0; t0 < T; t0 += 8) {    // 1000 = 125 * 8
        float d[8];
#pragma unroll
        for (int j = 0; j < 8; ++j) d[j] = drive_t[(t0 + j) * B + b];
#pragma unroll
        for (int j = 0; j < 8; ++j) {
            v = ALPHA * v + d[j] - V_TH * z;
            z = (v - V_TH > 0.0f) ? 1.0f : 0.0f;
            vout[t0 + j] = v;
            zout[t0 + j] = z;
        }
    }
}

extern "C" void kernel_launch(void* const* d_in, const int* in_sizes, int n_in,
                              void* d_out, int out_size, void* d_ws, size_t ws_size,
                              hipStream_t stream) {
    const float* x = (const float*)d_in[0];   // [B,T,N]
    const float* w = (const float*)d_in[1];   // [N]
    float* out = (float*)d_out;               // v[B,T] ++ z[B,T]
    float* drive_t = (float*)d_ws;            // [T,B] scratch, 512 KB

    // 128000 rows, 4 rows (waves) per 256-thread block -> 32000 blocks
    lif_dot_kernel<<<(B * T) / 4, 256, 0, stream>>>(x, w, drive_t);
    // single small block; same stream orders it after the dot kernel
    lif_scan_kernel<<<1, 128, 0, stream>>>(drive_t, out);
}